// Round 1
// 477.097 us; speedup vs baseline: 1.0988x; 1.0988x over previous
//
#include <hip/hip_runtime.h>
#include <cstddef>

// Problem constants
#define NBATCH 16384
// XD=64, AD=16, NC=8, PEN=10 -> c = 1/(2*PEN) = 0.05, DELTA=1, ITERS=250

// ---------------------------------------------------------------------------
// Compile-time FISTA momentum coefficients beta_i = (t_i - 1)/t_{i+1}
// ---------------------------------------------------------------------------
struct Betas {
  float b[250];
  static constexpr double csqrt(double x) {
    double g = x > 1.0 ? x : 1.0;
    for (int i = 0; i < 64; ++i) g = 0.5 * (g + x / g);
    return g;
  }
  constexpr Betas() : b{} {
    double tk = 1.0;
    for (int i = 0; i < 250; ++i) {
      double tk1 = 0.5 * (1.0 + csqrt(1.0 + 4.0 * tk * tk));
      b[i] = (float)((tk - 1.0) / tk1);
      tk = tk1;
    }
  }
};
__device__ constexpr Betas BETAS{};

// DPP helpers (VALU pipe — zero DS ops).
// quad_perm broadcasts: 0x00/0x55/0xAA/0xFF ; quad xor1=0xB1, xor2=0x4E
// row_ror:N = 0x120|N. NOTE: only direction-agnostic patterns are safe:
// full 16-lane rotate-sums (1,2,4,8) work for either ror direction; partial
// rotate-sums are direction-dependent — use __shfl_xor for sub-row groups.
template <int CTRL>
__device__ __forceinline__ float fdpp(float v) {
  return __int_as_float(
      __builtin_amdgcn_mov_dpp(__float_as_int(v), CTRL, 0xF, 0xF, true));
}
// rotate-sum over a 16-lane row: every lane ends with the row total
__device__ __forceinline__ float rowsum16(float p) {
  p += fdpp<0x121>(p);
  p += fdpp<0x122>(p);
  p += fdpp<0x124>(p);
  p += fdpp<0x128>(p);
  return p;
}

// ---------------------------------------------------------------------------
// K1 (v2): gh[b][r] = Qc_flat[r][:] . x[b][:] + cc_flat[r]
// Block = 64 batches x 128 rows.  Grid = 256 batch-blocks x 4 row-blocks.
// Qc rows for the block (32 KB) are staged once into LDS with coalesced
// float4 loads; compute reads them as wave-uniform ds_read_b128 broadcasts
// (replaces the old per-thread L2 round-trips, which were latency-bound).
// Output: each lane writes 8 consecutive float4 = one full 128-B line of
// gh[b], so no LDS transpose is needed.
// ---------------------------------------------------------------------------
__global__ __launch_bounds__(256) void cbf_k1_gh(
    const float* __restrict__ Qc, const float* __restrict__ cc,
    const float* __restrict__ X, float* __restrict__ gh) {
  __shared__ float qt[128 * 64];   // staged Qc rows [r-local 128][64]
  __shared__ float cct[128];
  const int tid = threadIdx.x;
  const int e   = tid & 63;        // batch lane
  const int rc  = tid >> 6;        // row chunk (32 rows each)
  const int b0  = (blockIdx.x & 255) * 64;
  const int r0  = (blockIdx.x >> 8) * 128;

  // ---- stage Qc rows r0..r0+127 (2048 float4s, 8 per thread) + cc ----------
  {
    const float4* qsrc = (const float4*)(Qc + (size_t)r0 * 64);
    float4* qdst = (float4*)qt;
#pragma unroll
    for (int i = 0; i < 8; ++i) qdst[i * 256 + tid] = qsrc[i * 256 + tid];
    if (tid < 32) ((float4*)cct)[tid] = ((const float4*)(cc + r0))[tid];
  }

  // x for this lane's batch element (64 floats in registers)
  float4 xr[16];
  {
    const float4* xp = (const float4*)(X + (size_t)(b0 + e) * 64);
#pragma unroll
    for (int c = 0; c < 16; ++c) xr[c] = xp[c];
  }
  __syncthreads();

  const int rcu = __builtin_amdgcn_readfirstlane(rc);
  const float* qrow = qt + rcu * 32 * 64;   // this wave's 32 rows
  float* ob = gh + (size_t)(b0 + e) * 512 + r0 + rcu * 32;

#pragma unroll 2
  for (int rg = 0; rg < 8; ++rg) {
    float o[4];
#pragma unroll
    for (int j = 0; j < 4; ++j) {
      const float4* w = (const float4*)(qrow + (rg * 4 + j) * 64);
      float a0 = 0.f, a1 = 0.f;
#pragma unroll
      for (int c = 0; c < 16; ++c) {
        float4 wv = w[c];            // wave-uniform ds_read_b128 (broadcast)
        a0 = fmaf(wv.x, xr[c].x, a0);
        a1 = fmaf(wv.y, xr[c].y, a1);
        a0 = fmaf(wv.z, xr[c].z, a0);
        a1 = fmaf(wv.w, xr[c].w, a1);
      }
      o[j] = a0 + a1 + cct[rcu * 32 + rg * 4 + j];
    }
    *(float4*)(ob + rg * 4) = *(const float4*)o;  // fills one 128-B line over rg
  }
}

// ---------------------------------------------------------------------------
// K2: per-element setup, one wave per element, 4 elements/block.
// Phase A uses DPP full-row rotate-sums (direction-safe); sub-row group
// reductions use __shfl_xor (involutive, direction-unambiguous).
// ---------------------------------------------------------------------------
#define XOFF  0
#define BVOFF 64
#define BOFF  72
#define GHOFF (72 + 1024)          // 1096, gh rows padded to 68
#define LGOFF (1096 + 544)         // 1640, Lg rows padded to 20
#define AXOFF (1640 + 160)         // 1800, ax[64]
#define ESTR  (1800 + 64)          // 1864 floats per element

__global__ __launch_bounds__(256) void cbf_k2_setup(
    const float* __restrict__ X, const float* __restrict__ Abat,
    const float* __restrict__ Bbat, const float* __restrict__ cc,
    const float* __restrict__ dc, const float* __restrict__ a_des,
    const float* __restrict__ gh, float* __restrict__ S_ws,
    float* __restrict__ LgT_ws, float* __restrict__ qu_ws) {
  __shared__ float smem[4 * ESTR];
  const int tid  = threadIdx.x;
  const int sub  = tid >> 6;
  const int lane = tid & 63;
  const int b    = blockIdx.x * 4 + sub;
  float* sm = smem + sub * ESTR;

  // ---- stage: x, B [i][a], gh (padded rows) -> LDS --------------------------
  const float xi = X[(size_t)b * 64 + lane];
  sm[XOFF + lane] = xi;
  {
    const float4* bp = (const float4*)(Bbat + (size_t)b * 1024);
#pragma unroll
    for (int n = 0; n < 4; ++n) {
      float4 v = bp[n * 64 + lane];
      *(float4*)&sm[BOFF + n * 256 + lane * 4] = v;
    }
  }
  {
    const float4* gp = (const float4*)(gh + (size_t)b * 512);
    float4 g0 = gp[lane];        // floats [lane*4, +4)
    float4 g1 = gp[64 + lane];   // floats [256+lane*4, +4)
    const int f0 = lane * 4, f1 = 256 + lane * 4;
    *(float4*)&sm[GHOFF + (f0 >> 6) * 68 + (f0 & 63)] = g0;
    *(float4*)&sm[GHOFF + (f1 >> 6) * 68 + (f1 & 63)] = g1;
  }
  __syncthreads();

  // ---- phase A: Ax, coalesced A stream + DPP full-row reductions ------------
  {
    const float4* ap = (const float4*)(Abat + (size_t)b * 4096);
    const int cg = lane & 15;      // column group (16-lane DPP row)
    const int rg = lane >> 4;      // row-in-chunk
    const float4 xv = *(const float4*)&sm[XOFF + cg * 4];
#pragma unroll
    for (int n = 0; n < 16; ++n) {
      float4 av = ap[n * 64 + lane];
      float p = av.x * xv.x + av.y * xv.y + av.z * xv.z + av.w * xv.w;
      p = rowsum16(p);                       // VALU-only, direction-safe
      if (cg == 0) sm[AXOFF + n * 4 + rg] = p;
    }
  }
  __syncthreads();

  // ---- phase B: bvec[m] via 8-wide partial dots + xor group sums ------------
  {
    const int m  = lane >> 3;
    const int ig = lane & 7;
    const float4 ghA = *(const float4*)&sm[GHOFF + m * 68 + ig * 8];
    const float4 ghB = *(const float4*)&sm[GHOFF + m * 68 + ig * 8 + 4];
    const float4 xA  = *(const float4*)&sm[XOFF + ig * 8];
    const float4 xB  = *(const float4*)&sm[XOFF + ig * 8 + 4];
    const float4 axA = *(const float4*)&sm[AXOFF + ig * 8];
    const float4 axB = *(const float4*)&sm[AXOFF + ig * 8 + 4];
    const float4 ccA = *(const float4*)(cc + m * 64 + ig * 8);
    const float4 ccB = *(const float4*)(cc + m * 64 + ig * 8 + 4);
    float p1 = ghA.x * xA.x + ghA.y * xA.y + ghA.z * xA.z + ghA.w * xA.w
             + ghB.x * xB.x + ghB.y * xB.y + ghB.z * xB.z + ghB.w * xB.w;
    float p2 = ghA.x * axA.x + ghA.y * axA.y + ghA.z * axA.z + ghA.w * axA.w
             + ghB.x * axB.x + ghB.y * axB.y + ghB.z * axB.z + ghB.w * axB.w;
    float p3 = ccA.x * xA.x + ccA.y * xA.y + ccA.z * xA.z + ccA.w * xA.w
             + ccB.x * xB.x + ccB.y * xB.y + ccB.z * xB.z + ccB.w * xB.w;
    p1 += __shfl_xor(p1, 1); p1 += __shfl_xor(p1, 2); p1 += __shfl_xor(p1, 4);
    p2 += __shfl_xor(p2, 1); p2 += __shfl_xor(p2, 2); p2 += __shfl_xor(p2, 4);
    p3 += __shfl_xor(p3, 1); p3 += __shfl_xor(p3, 2); p3 += __shfl_xor(p3, 4);
    if (ig == 0) {
      // g = 0.5*(x.gh + cc.x) - dc ; bvec = (Ax.gh) + g
      sm[BVOFF + m] = p2 + 0.5f * (p1 + p3) - dc[m];
    }
  }

  // ---- phase C: Lg[m][a] = -sum_i gh[m][i]*B[i][a] --------------------------
  const int mq  = lane >> 3;
  const int ap2 = lane & 7;
  {
    float acc0 = 0.f, acc1 = 0.f;
#pragma unroll
    for (int c = 0; c < 16; ++c) {
      float4 gv = *(const float4*)&sm[GHOFF + mq * 68 + 4 * c];
#pragma unroll
      for (int n = 0; n < 4; ++n) {
        float2 bv2 = *(const float2*)&sm[BOFF + (4 * c + n) * 16 + 2 * ap2];
        float gvn = (n == 0) ? gv.x : ((n == 1) ? gv.y : ((n == 2) ? gv.z : gv.w));
        acc0 = fmaf(gvn, bv2.x, acc0);
        acc1 = fmaf(gvn, bv2.y, acc1);
      }
    }
    const float lg0 = -acc0, lg1 = -acc1;
    LgT_ws[(size_t)b * 128 + (2 * ap2) * 8 + mq]     = lg0;  // LgT[a][m]
    LgT_ws[(size_t)b * 128 + (2 * ap2 + 1) * 8 + mq] = lg1;
    sm[LGOFF + mq * 20 + 2 * ap2]     = lg0;
    sm[LGOFF + mq * 20 + 2 * ap2 + 1] = lg1;
  }
  __syncthreads();

  // ---- phase D: S[k][l] = 0.5 * <Lg_k, Lg_l> --------------------------------
  const int kq = lane >> 3;
  const int lq = lane & 7;
  {
    float s = 0.f;
#pragma unroll
    for (int c = 0; c < 4; ++c) {
      float4 ka = *(const float4*)&sm[LGOFF + kq * 20 + 4 * c];
      float4 la = *(const float4*)&sm[LGOFF + lq * 20 + 4 * c];
      s = fmaf(ka.x, la.x, s);
      s = fmaf(ka.y, la.y, s);
      s = fmaf(ka.z, la.z, s);
      s = fmaf(ka.w, la.w, s);
    }
    S_ws[(size_t)b * 64 + kq * 8 + lq] = 0.5f * s;
  }

  // ---- phase E: qu[k] = bvec[k] - <Lg_k, a_des> (xor group sum) -------------
  {
    float2 ad2 = *(const float2*)(a_des + (size_t)b * 16 + 2 * lq);
    float2 kg  = *(const float2*)&sm[LGOFF + kq * 20 + 2 * lq];
    float p = kg.x * ad2.x + kg.y * ad2.y;
    p += __shfl_xor(p, 1);
    p += __shfl_xor(p, 2);
    p += __shfl_xor(p, 4);
    if (lq == 0) qu_ws[(size_t)b * 8 + kq] = sm[BVOFF + kq] - p;
  }
}

// ---------------------------------------------------------------------------
// K3: dual FISTA, 4 lanes per element; lane q owns rows q and q+4 of S.
// All cross-lane traffic is DPP quad_perm on the VALU pipe (zero DS ops).
// M = [[S+cI, cI],[cI,cI]] -> grad_u = S yu + c(yu+yv) - qu ; grad_v = c(yu+yv)
// lambda_max(M) = ((2c+mu)+sqrt(4c^2+mu^2))/2, mu = lambda_max(S) (power it.)
// ---------------------------------------------------------------------------
__global__ __launch_bounds__(256) void cbf_k3_fista(
    const float* __restrict__ S_ws, const float* __restrict__ qu_ws,
    const float* __restrict__ LgT_ws, const float* __restrict__ a_des,
    float* __restrict__ out) {
  const int gt = blockIdx.x * 256 + threadIdx.x;
  const int e  = gt >> 2;
  const int q  = gt & 3;

  const float4* Sp = (const float4*)(S_ws + (size_t)e * 64);
  const float4 sl0 = Sp[q * 2],       sl1 = Sp[q * 2 + 1];        // row q
  const float4 sh0 = Sp[(q + 4) * 2], sh1 = Sp[(q + 4) * 2 + 1];  // row q+4
  const float qu_lo = qu_ws[(size_t)e * 8 + q];
  const float qu_hi = qu_ws[(size_t)e * 8 + q + 4];

#define MV(ylo, yhi, alo, ahi) do {                                          \
    float b0 = fdpp<0x00>(ylo), b1 = fdpp<0x55>(ylo);                        \
    float b2 = fdpp<0xAA>(ylo), b3 = fdpp<0xFF>(ylo);                        \
    float b4 = fdpp<0x00>(yhi), b5 = fdpp<0x55>(yhi);                        \
    float b6 = fdpp<0xAA>(yhi), b7 = fdpp<0xFF>(yhi);                        \
    float t0 = sl0.x * b0, t1 = sl0.y * b1;                                  \
    t0 = fmaf(sl0.z, b2, t0); t1 = fmaf(sl0.w, b3, t1);                      \
    t0 = fmaf(sl1.x, b4, t0); t1 = fmaf(sl1.y, b5, t1);                      \
    t0 = fmaf(sl1.z, b6, t0); t1 = fmaf(sl1.w, b7, t1);                      \
    alo = t0 + t1;                                                           \
    float u0 = sh0.x * b0, u1 = sh0.y * b1;                                  \
    u0 = fmaf(sh0.z, b2, u0); u1 = fmaf(sh0.w, b3, u1);                      \
    u0 = fmaf(sh1.x, b4, u0); u1 = fmaf(sh1.y, b5, u1);                      \
    u0 = fmaf(sh1.z, b6, u0); u1 = fmaf(sh1.w, b7, u1);                      \
    ahi = u0 + u1;                                                           \
  } while (0)

  // power iteration for mu = lambda_max(S)
  float vl = 1.f, vh = 1.f, svl, svh;
#pragma unroll 4
  for (int it = 0; it < 40; ++it) {
    MV(vl, vh, svl, svh);
    float am = fmaxf(fabsf(svl), fabsf(svh));
    am = fmaxf(am, fdpp<0xB1>(am));   // xor 1 within quad
    am = fmaxf(am, fdpp<0x4E>(am));   // xor 2 within quad
    float r = 1.f / fmaxf(am, 1e-30f);
    vl = svl * r; vh = svh * r;
  }
  MV(vl, vh, svl, svh);
  float num = vl * svl + vh * svh;
  float den = vl * vl + vh * vh;
  num += fdpp<0xB1>(num); den += fdpp<0xB1>(den);
  num += fdpp<0x4E>(num); den += fdpp<0x4E>(den);
  float mu = fmaxf((num / fmaxf(den, 1e-30f)) * 1.001f, 0.f);
  const float lmax = 0.5f * ((0.1f + mu) + sqrtf(fmaf(mu, mu, 0.01f)));
  const float t = 1.0f / (lmax + 1e-6f);

  // FISTA, 250 iterations — pure VALU
  float yul = 0.f, yuh = 0.f, yvl = 0.f, yvh = 0.f;
  float lul = 0.f, luh = 0.f, lvl_ = 0.f, lvh = 0.f;
#pragma unroll 5
  for (int it = 0; it < 250; ++it) {
    const float beta = BETAS.b[it];
    const float wl = 0.05f * (yul + yvl);   // c*(yu+yv) = grad_v
    const float wh = 0.05f * (yuh + yvh);
    float al, ah;
    MV(yul, yuh, al, ah);
    const float gul = al + wl - qu_lo;
    const float guh = ah + wh - qu_hi;
    const float lunl = fmaxf(fmaf(-t, gul, yul), 0.f);
    const float lunh = fmaxf(fmaf(-t, guh, yuh), 0.f);
    const float lvnl = fmaxf(fmaf(-t, wl, yvl), 0.f);
    const float lvnh = fmaxf(fmaf(-t, wh, yvh), 0.f);
    yul = fmaf(beta, lunl - lul, lunl); lul = lunl;
    yuh = fmaf(beta, lunh - luh, lunh); luh = lunh;
    yvl = fmaf(beta, lvnl - lvl_, lvnl); lvl_ = lvnl;
    yvh = fmaf(beta, lvnh - lvh, lvnh); lvh = lvnh;
  }
#undef MV

  // primal recovery: lane q computes a[q*4 .. q*4+3]
  const float l0 = fdpp<0x00>(lul), l1 = fdpp<0x55>(lul);
  const float l2 = fdpp<0xAA>(lul), l3 = fdpp<0xFF>(lul);
  const float l4 = fdpp<0x00>(luh), l5 = fdpp<0x55>(luh);
  const float l6 = fdpp<0xAA>(luh), l7 = fdpp<0xFF>(luh);
  const float4* Lp = (const float4*)(LgT_ws + (size_t)e * 128 + q * 32);
  const float4 ad  = *(const float4*)(a_des + (size_t)e * 16 + q * 4);
  float o[4];
#pragma unroll
  for (int j = 0; j < 4; ++j) {
    float4 ga = Lp[j * 2], gb = Lp[j * 2 + 1];   // LgT[a = q*4+j][0..7]
    float s = ga.x * l0 + ga.y * l1 + ga.z * l2 + ga.w * l3
            + gb.x * l4 + gb.y * l5 + gb.z * l6 + gb.w * l7;
    o[j] = 0.5f * s;
  }
  float4 ov;
  ov.x = ad.x + o[0]; ov.y = ad.y + o[1];
  ov.z = ad.z + o[2]; ov.w = ad.w + o[3];
  *(float4*)(out + (size_t)e * 16 + q * 4) = ov;
}

// ---------------------------------------------------------------------------
extern "C" void kernel_launch(void* const* d_in, const int* in_sizes, int n_in,
                              void* d_out, int out_size, void* d_ws, size_t ws_size,
                              hipStream_t stream) {
  (void)in_sizes; (void)n_in; (void)out_size; (void)ws_size;
  const float* a_des = (const float*)d_in[0];
  const float* x     = (const float*)d_in[1];
  const float* A     = (const float*)d_in[2];
  const float* B     = (const float*)d_in[3];
  const float* Qc    = (const float*)d_in[4];
  const float* cc    = (const float*)d_in[5];
  const float* dc    = (const float*)d_in[6];
  float* out = (float*)d_out;

  // workspace layout (floats): gh 16384*512 | S 16384*64 | LgT 16384*128 | qu 16384*8
  float* gh  = (float*)d_ws;
  float* S   = gh  + (size_t)NBATCH * 512;
  float* LgT = S   + (size_t)NBATCH * 64;
  float* qu  = LgT + (size_t)NBATCH * 128;

  hipLaunchKernelGGL(cbf_k1_gh, dim3(1024), dim3(256), 0, stream, Qc, cc, x, gh);
  hipLaunchKernelGGL(cbf_k2_setup, dim3(4096), dim3(256), 0, stream,
                     x, A, B, cc, dc, a_des, gh, S, LgT, qu);
  hipLaunchKernelGGL(cbf_k3_fista, dim3(256), dim3(256), 0, stream,
                     S, qu, LgT, a_des, out);
}